// Round 2
// baseline (862.393 us; speedup 1.0000x reference)
//
#include <hip/hip_runtime.h>
#include <math.h>

#define INVALID_TOKEN_ID (-1)
constexpr int BB = 128;              // batch
constexpr int KK = 8;                // spec length
constexpr int VV = 128000;           // vocab
constexpr int ROWS = BB * (KK + 1);  // 1152 rows
constexpr int THREADS = 384;         // 6 waves; 5 blocks/CU -> 30/32 waves, all 1152 blocks resident
constexpr int NV4 = VV / 4;          // 32000 float4 per row

// One block per row: float4-coalesced argmax with first-occurrence tie-break
// (matches jnp.argmax — ties at the max DO occur with 128k uniforms/row).
// Last-finishing block of each batch row (9 rows) runs the accept-mask
// finalize inline (device-scope release/acquire, valid across XCDs).
__global__ __launch_bounds__(THREADS) void rejsample_fused_kernel(
    const float* __restrict__ probs,
    const int* __restrict__ draft,
    int* __restrict__ amax,       // d_ws: ROWS ints
    int* __restrict__ counters,   // d_ws + ROWS: BB ints, pre-zeroed
    int* __restrict__ out) {
    const int row = blockIdx.x;
    const int tid = threadIdx.x;
    const float4* __restrict__ p4 = (const float4*)(probs + (size_t)row * VV);

    // Two independent accumulator streams -> 2x loads in flight, half the
    // serial cmp/cndmask chain. Indices monotone within each stream, so
    // strict '>' preserves first-occurrence; merge is exact lex-compare.
    float bestA = -INFINITY, bestB = -INFINITY;
    int idxA = VV, idxB = VV;

    int i = tid;
    #pragma unroll 2
    for (; i + THREADS < NV4; i += 2 * THREADS) {
        float4 va = p4[i];
        float4 vb = p4[i + THREADS];
        int ba = i * 4;
        int bb = (i + THREADS) * 4;
        if (va.x > bestA) { bestA = va.x; idxA = ba; }
        if (va.y > bestA) { bestA = va.y; idxA = ba + 1; }
        if (va.z > bestA) { bestA = va.z; idxA = ba + 2; }
        if (va.w > bestA) { bestA = va.w; idxA = ba + 3; }
        if (vb.x > bestB) { bestB = vb.x; idxB = bb; }
        if (vb.y > bestB) { bestB = vb.y; idxB = bb + 1; }
        if (vb.z > bestB) { bestB = vb.z; idxB = bb + 2; }
        if (vb.w > bestB) { bestB = vb.w; idxB = bb + 3; }
    }
    if (i < NV4) {  // tail: at most one float4 left in this thread's stream
        float4 va = p4[i];
        int ba = i * 4;
        if (va.x > bestA) { bestA = va.x; idxA = ba; }
        if (va.y > bestA) { bestA = va.y; idxA = ba + 1; }
        if (va.z > bestA) { bestA = va.z; idxA = ba + 2; }
        if (va.w > bestA) { bestA = va.w; idxA = ba + 3; }
    }
    // merge stream B into A (value desc, index asc)
    if (bestB > bestA || (bestB == bestA && idxB < idxA)) {
        bestA = bestB;
        idxA = idxB;
    }

    // Wave (64-lane) lex reduction.
    #pragma unroll
    for (int off = 32; off > 0; off >>= 1) {
        float ov = __shfl_down(bestA, off, 64);
        int   oi = __shfl_down(idxA, off, 64);
        if (ov > bestA || (ov == bestA && oi < idxA)) {
            bestA = ov;
            idxA = oi;
        }
    }

    // Cross-wave reduction via LDS (6 waves).
    __shared__ float s_v[THREADS / 64];
    __shared__ int   s_i[THREADS / 64];
    const int wave = tid >> 6;
    const int lane = tid & 63;
    if (lane == 0) {
        s_v[wave] = bestA;
        s_i[wave] = idxA;
    }
    __syncthreads();

    if (tid == 0) {
        #pragma unroll
        for (int w = 1; w < THREADS / 64; ++w) {
            if (s_v[w] > bestA || (s_v[w] == bestA && s_i[w] < idxA)) {
                bestA = s_v[w];
                idxA = s_i[w];
            }
        }
        const int b = row / (KK + 1);
        // Publish this row's argmax (device scope: XCD L2s not coherent).
        __hip_atomic_store(&amax[row], idxA, __ATOMIC_RELEASE,
                           __HIP_MEMORY_SCOPE_AGENT);
        int ticket = __hip_atomic_fetch_add(&counters[b], 1, __ATOMIC_ACQ_REL,
                                            __HIP_MEMORY_SCOPE_AGENT);
        if (ticket == KK) {
            // Last of the 9 blocks for batch row b: finalize accept mask.
            int a[KK + 1];
            #pragma unroll
            for (int j = 0; j <= KK; ++j) {
                a[j] = __hip_atomic_load(&amax[b * (KK + 1) + j],
                                         __ATOMIC_ACQUIRE,
                                         __HIP_MEMORY_SCOPE_AGENT);
            }
            int r = 0;
            while (r < KK && a[r] == draft[b * KK + r]) ++r;
            #pragma unroll
            for (int j = 0; j <= KK; ++j) {
                out[b * (KK + 1) + j] = (j <= r) ? a[j] : INVALID_TOKEN_ID;
            }
        }
    }
}

extern "C" void kernel_launch(void* const* d_in, const int* in_sizes, int n_in,
                              void* d_out, int out_size, void* d_ws, size_t ws_size,
                              hipStream_t stream) {
    const int*   draft = (const int*)d_in[0];    // [B, K] int32
    const float* probs = (const float*)d_in[1];  // [B*(K+1), V] fp32
    int* out      = (int*)d_out;                 // [B, K+1] int32
    int* amax     = (int*)d_ws;                  // ROWS ints
    int* counters = amax + ROWS;                 // BB ints

    // d_ws is poisoned 0xAA before every launch — zero the counters.
    hipMemsetAsync(counters, 0, BB * sizeof(int), stream);
    rejsample_fused_kernel<<<ROWS, THREADS, 0, stream>>>(probs, draft, amax,
                                                         counters, out);
}